// Round 3
// baseline (346.748 us; speedup 1.0000x reference)
//
#include <hip/hip_runtime.h>
#include <hip/hip_bf16.h>

// M[t, i*768+p, j*768+q] = A[t,i,j] * exp(-maha - 0.5*logdet(D_tij)), row-normalized.
// D is 2x2 SPD -> closed-form inverse + det^-1/2. One block per output row
// (36864 rows), 192 threads x 8 consecutive cols, row sum reduced in-block =>
// single pass, write-only HBM traffic (226 MB fp32 out).
// Inputs fp32 (runtime sniff keeps a bf16 hedge); OUTPUT IS FP32 (harness doc:
// reference returns float32 -> d_out is float*). Round-2 failure was writing
// bf16-packed words into this fp32 buffer (half-written -> full-scale error).

typedef unsigned int u32;
typedef unsigned short u16;

namespace {
constexpr float GAMMA_C   = 0.3f;
constexpr float JITTER_C  = 1e-5f;
constexpr float ELL_MIN_C = 0.05f;
constexpr float ELL_MAX_C = 10.0f;
constexpr int   NPT     = 768;
constexpr int   TSTEPS  = 24;
constexpr int   THREADS = 192;                 // 3 waves; each thread -> 8 cols
constexpr int   ROWS    = TSTEPS * 2 * NPT;    // 36864
}

__device__ __forceinline__ float bf2f(u16 h) {
    return __uint_as_float(((u32)h) << 16);
}

__global__ __launch_bounds__(THREADS) void vlk_kernel(
    const void* __restrict__ Sv,         // [768,2]
    const void* __restrict__ muv,        // [24,4]
    const void* __restrict__ Sgv,        // [24,4,4]
    const void* __restrict__ Av,         // [24,2,2]
    const void* __restrict__ rlv,        // [2,2]
    float* __restrict__ out)             // [24,1536,1536] fp32
{
    // ---- input dtype sniff (grid-uniform): bf16 raw_ell words 0 and 2 decode
    // to ~-2.25; an fp32 buffer puts random-exponent mantissa halves there.
    const u16* rl16 = (const u16*)rlv;
    const float sn0 = bf2f(rl16[0]);
    const float sn2 = bf2f(rl16[2]);
    const bool in_bf16 = (sn0 > -8.0f && sn0 < -0.5f && sn2 > -8.0f && sn2 < -0.5f);

    const int tid = threadIdx.x;
    const int row = blockIdx.x;                 // (t, i, p) flattened
    const int t   = row / (2 * NPT);
    const int rem = row - t * (2 * NPT);
    const int i   = rem / NPT;                  // row-block index (0/1)
    const int p   = rem - i * NPT;

    const int c0    = tid * 8;                  // first column for this thread
    const int jj    = (c0 >= NPT) ? 1 : 0;      // col-block index
    const int qbase = c0 - jj * NPT;            // 0..760, multiple of 8

    // ---- scalar param loads (all L1-hit, redundant per thread) ----
    #define LD(base, idx) (in_bf16 ? bf2f(((const u16*)(base))[idx]) : ((const float*)(base))[idx])

    float mu[4];
#pragma unroll
    for (int k = 0; k < 4; ++k) mu[k] = LD(muv, t * 4 + k);

    const int bi = 2 * i, bj = 2 * jj;
    float Sg[4][4];
#pragma unroll
    for (int r = 0; r < 4; ++r)
#pragma unroll
        for (int c = 0; c < 4; ++c) Sg[r][c] = LD(Sgv, t * 16 + r * 4 + c);

    const float a  = LD(Av, (t * 2 + i) * 2 + jj);
    const float rl = LD(rlv, i * 2 + jj);
    const float ell = ELL_MIN_C + (ELL_MAX_C - ELL_MIN_C) / (1.0f + __expf(-rl));

    // shift_r = mu[2i+r] - gamma*mu[2j+r]   (dt = 1)
    const float shift0 = mu[bi]     - GAMMA_C * mu[bj];
    const float shift1 = mu[bi + 1] - GAMMA_C * mu[bj + 1];

    // BSB[r,s] = Sg[2i+r][2i+s] - g*Sg[2i+r][2j+s] - g*Sg[2j+r][2i+s] + g^2*Sg[2j+r][2j+s]
    const float g = GAMMA_C;
    const float b00 = Sg[bi][bi]     - g*Sg[bi][bj]     - g*Sg[bj][bi]     + g*g*Sg[bj][bj];
    const float b01 = Sg[bi][bi+1]   - g*Sg[bi][bj+1]   - g*Sg[bj][bi+1]   + g*g*Sg[bj][bj+1];
    const float b11 = Sg[bi+1][bi+1] - g*Sg[bi+1][bj+1] - g*Sg[bj+1][bi+1] + g*g*Sg[bj+1][bj+1];

    const float e2  = ell * ell + JITTER_C;
    const float D00 = e2 + 2.0f * b00;
    const float D01 =      2.0f * b01;
    const float D11 = e2 + 2.0f * b11;
    const float det  = D00 * D11 - D01 * D01;       // SPD -> det > 0
    const float rdet = 1.0f / det;
    const float i00  =  D11 * rdet;
    const float i01  = -D01 * rdet;
    const float i11  =  D00 * rdet;
    const float coef = a * rsqrtf(det);             // A * exp(-0.5*logdet)

    // ---- S loads: uniform point p + 8 consecutive q points ----
    float sp0, sp1, sq0[8], sq1[8];
    if (in_bf16) {
        const u32* S32 = (const u32*)Sv;            // one u32 = one point (2 bf16)
        const u32 wp = S32[p];
        sp0 = __uint_as_float(wp << 16);
        sp1 = __uint_as_float(wp & 0xffff0000u);
        uint4 wa = *((const uint4*)(S32 + qbase));
        uint4 wb = *((const uint4*)(S32 + qbase + 4));
        u32 wq[8] = {wa.x, wa.y, wa.z, wa.w, wb.x, wb.y, wb.z, wb.w};
#pragma unroll
        for (int k = 0; k < 8; ++k) {
            sq0[k] = __uint_as_float(wq[k] << 16);
            sq1[k] = __uint_as_float(wq[k] & 0xffff0000u);
        }
    } else {
        const float* Sf = (const float*)Sv;         // [768,2] fp32
        sp0 = Sf[2 * p];
        sp1 = Sf[2 * p + 1];
        const float4* q4 = (const float4*)(Sf + 2 * qbase);  // 64 B aligned
        float4 q0 = q4[0], q1 = q4[1], q2 = q4[2], q3 = q4[3];
        sq0[0]=q0.x; sq1[0]=q0.y; sq0[1]=q0.z; sq1[1]=q0.w;
        sq0[2]=q1.x; sq1[2]=q1.y; sq0[3]=q1.z; sq1[3]=q1.w;
        sq0[4]=q2.x; sq1[4]=q2.y; sq0[5]=q2.z; sq1[5]=q2.w;
        sq0[6]=q3.x; sq1[6]=q3.y; sq0[7]=q3.z; sq1[7]=q3.w;
    }

    float vals[8];
    float lsum = 0.0f;
#pragma unroll
    for (int k = 0; k < 8; ++k) {
        float h0 = sp0 - sq0[k] - shift0;
        float h1 = sp1 - sq1[k] - shift1;
        float maha = (i00 * h0 + 2.0f * i01 * h1) * h0 + i11 * h1 * h1;
        float v = coef * __expf(-maha);
        vals[k] = v;
        lsum += v;
    }

    // ---- row-sum reduction: wave shuffle + 3-slot LDS ----
    float s = lsum;
#pragma unroll
    for (int off = 32; off > 0; off >>= 1) s += __shfl_down(s, off, 64);
    __shared__ float red[THREADS / 64];
    if ((tid & 63) == 0) red[tid >> 6] = s;
    __syncthreads();
    const float tot = red[0] + red[1] + red[2];
    const float inv = 1.0f / fmaxf(tot, 1e-8f);     // clip(sum, 1e-8)

    // ---- normalize + two 16 B fp32 stores (32 B contiguous per thread) ----
    float4* o4 = (float4*)(out + (size_t)row * (2 * NPT) + c0);
    float4 oa, ob;
    oa.x = vals[0] * inv; oa.y = vals[1] * inv; oa.z = vals[2] * inv; oa.w = vals[3] * inv;
    ob.x = vals[4] * inv; ob.y = vals[5] * inv; ob.z = vals[6] * inv; ob.w = vals[7] * inv;
    o4[0] = oa;
    o4[1] = ob;
}

extern "C" void kernel_launch(void* const* d_in, const int* in_sizes, int n_in,
                              void* d_out, int out_size, void* d_ws, size_t ws_size,
                              hipStream_t stream) {
    vlk_kernel<<<ROWS, THREADS, 0, stream>>>(
        d_in[0],   // S
        d_in[1],   // mu_seq
        d_in[2],   // Sigma_seq
        d_in[3],   // A_seq
        d_in[4],   // raw_ell
        (float*)d_out);
}

// Round 4
// 239.458 us; speedup vs baseline: 1.4481x; 1.4481x over previous
//
#include <hip/hip_runtime.h>

// M[t, i*768+p, j*768+q] = A[t,i,j] * exp(-maha - 0.5*logdet(D_tij)), row-normalized.
// D is 2x2 SPD -> closed-form inverse, coef = A * det^-1/2.
// Structure: ONE WAVE PER OUTPUT ROW. Lane covers 24 cols interleaved as
// col = k*256 + lane*4 (k=0..5) -> every float4 store is lane-contiguous (1KB/instr).
// Row sum = in-register __shfl_xor butterfly: zero LDS, zero barriers (round-3
// kernel burned ~7.8e7 LDS bank-conflict cycles in its block reduction).
// Each wave processes 4 rows of the same (t,i): S-points + both jj param sets
// loaded/computed once per 6144 outputs. Inputs fp32, output fp32 (verified R3).

typedef unsigned int u32;

namespace {
constexpr float GAMMA_C   = 0.3f;
constexpr float JITTER_C  = 1e-5f;
constexpr float ELL_MIN_C = 0.05f;
constexpr float ELL_MAX_C = 10.0f;
constexpr int   NPT     = 768;
constexpr int   TSTEPS  = 24;
constexpr int   ROWS    = TSTEPS * 2 * NPT;   // 36864
constexpr int   W_ROWS  = 4;                  // rows per wave
constexpr int   WAVES   = 4;                  // waves per block
constexpr int   THREADS = WAVES * 64;         // 256
constexpr int   RPB     = W_ROWS * WAVES;     // 16 rows per block
constexpr int   BLOCKS  = ROWS / RPB;         // 2304
}

__global__ __launch_bounds__(THREADS) void vlk_kernel(
    const float* __restrict__ S,         // [768,2]
    const float* __restrict__ mu_seq,    // [24,4]
    const float* __restrict__ Sg,        // [24,4,4]
    const float* __restrict__ A,         // [24,2,2]
    const float* __restrict__ rl,        // [2,2]
    float* __restrict__ out)             // [24,1536,1536]
{
    const int w    = threadIdx.x >> 6;
    const int lane = threadIdx.x & 63;

    const int base = blockIdx.x * RPB;          // first row of this block
    const int t    = base / (2 * NPT);
    const int rem  = base - t * (2 * NPT);
    const int i    = rem / NPT;                 // row-block index (uniform per block)
    const int p0   = rem - i * NPT + w * W_ROWS;

    // ---- per-(t,i) params for BOTH jj, once per wave-lifetime ----
    float mu[4];
#pragma unroll
    for (int k = 0; k < 4; ++k) mu[k] = mu_seq[t * 4 + k];
    float Sgm[4][4];
#pragma unroll
    for (int r = 0; r < 4; ++r)
#pragma unroll
        for (int c = 0; c < 4; ++c) Sgm[r][c] = Sg[t * 16 + r * 4 + c];

    float shift0[2], shift1[2], i00[2], i01[2], i11[2], coef[2];
    const int bi = 2 * i;
    const float g = GAMMA_C;
#pragma unroll
    for (int jj = 0; jj < 2; ++jj) {
        const int bj = 2 * jj;
        shift0[jj] = mu[bi]     - g * mu[bj];
        shift1[jj] = mu[bi + 1] - g * mu[bj + 1];
        const float b00 = Sgm[bi][bi]     - g*Sgm[bi][bj]     - g*Sgm[bj][bi]     + g*g*Sgm[bj][bj];
        const float b01 = Sgm[bi][bi+1]   - g*Sgm[bi][bj+1]   - g*Sgm[bj][bi+1]   + g*g*Sgm[bj][bj+1];
        const float b11 = Sgm[bi+1][bi+1] - g*Sgm[bi+1][bj+1] - g*Sgm[bj+1][bi+1] + g*g*Sgm[bj+1][bj+1];
        const float rlv = rl[i * 2 + jj];
        const float ell = ELL_MIN_C + (ELL_MAX_C - ELL_MIN_C) / (1.0f + __expf(-rlv));
        const float e2  = ell * ell + JITTER_C;
        const float D00 = e2 + 2.0f * b00;
        const float D01 =      2.0f * b01;
        const float D11 = e2 + 2.0f * b11;
        const float det  = D00 * D11 - D01 * D01;       // SPD -> det > 0
        const float rdet = 1.0f / det;
        i00[jj] =  D11 * rdet;
        i01[jj] = -D01 * rdet;
        i11[jj] =  D00 * rdet;
        coef[jj] = A[(t * 2 + i) * 2 + jj] * rsqrtf(det);
    }

    // ---- S points for this lane's 12 q positions (shared by jj=0 and jj=1) ----
    // chunk m in 0..2: q = m*256 + lane*4 + {0..3}
    float sx[12], sy[12];
#pragma unroll
    for (int m = 0; m < 3; ++m) {
        const int q0 = m * 256 + lane * 4;
        const float4 a4 = *((const float4*)(S + 2 * q0));      // x0 y0 x1 y1
        const float4 b4 = *((const float4*)(S + 2 * q0 + 4));  // x2 y2 x3 y3
        sx[4*m+0] = a4.x; sy[4*m+0] = a4.y;
        sx[4*m+1] = a4.z; sy[4*m+1] = a4.w;
        sx[4*m+2] = b4.x; sy[4*m+2] = b4.y;
        sx[4*m+3] = b4.z; sy[4*m+3] = b4.w;
    }

    // ---- 4 rows per wave ----
#pragma unroll
    for (int r = 0; r < W_ROWS; ++r) {
        const int p = p0 + r;
        const float sp0 = S[2 * p];          // uniform per wave -> broadcast
        const float sp1 = S[2 * p + 1];

        float vals[24];
        float lsum = 0.0f;
#pragma unroll
        for (int k = 0; k < 6; ++k) {        // chunk: col = k*256 + lane*4
            const int jj = (k >= 3) ? 1 : 0;
            const int m  = k - 3 * jj;
            const float s0 = shift0[jj], s1 = shift1[jj];
            const float a0 = i00[jj], a1 = i01[jj], a2 = i11[jj], cf = coef[jj];
#pragma unroll
            for (int j = 0; j < 4; ++j) {
                const float h0 = sp0 - sx[4*m+j] - s0;
                const float h1 = sp1 - sy[4*m+j] - s1;
                const float maha = (a0 * h0 + 2.0f * a1 * h1) * h0 + a2 * h1 * h1;
                const float v = cf * __expf(-maha);
                vals[4*k+j] = v;
                lsum += v;
            }
        }

        // in-register wave reduction: all lanes end with the row total
#pragma unroll
        for (int off = 1; off < 64; off <<= 1) lsum += __shfl_xor(lsum, off, 64);
        const float inv = 1.0f / fmaxf(lsum, 1e-8f);    // clip(sum, 1e-8)

        float* op = out + (size_t)(base + w * W_ROWS + r) * (2 * NPT);
#pragma unroll
        for (int k = 0; k < 6; ++k) {
            float4 o;
            o.x = vals[4*k+0] * inv;
            o.y = vals[4*k+1] * inv;
            o.z = vals[4*k+2] * inv;
            o.w = vals[4*k+3] * inv;
            *((float4*)(op + k * 256 + lane * 4)) = o;
        }
    }
}

extern "C" void kernel_launch(void* const* d_in, const int* in_sizes, int n_in,
                              void* d_out, int out_size, void* d_ws, size_t ws_size,
                              hipStream_t stream) {
    vlk_kernel<<<BLOCKS, THREADS, 0, stream>>>(
        (const float*)d_in[0],   // S
        (const float*)d_in[1],   // mu_seq
        (const float*)d_in[2],   // Sigma_seq
        (const float*)d_in[3],   // A_seq
        (const float*)d_in[4],   // raw_ell
        (float*)d_out);
}